// Round 17
// baseline (74.912 us; speedup 1.0000x reference)
//
#include <hip/hip_runtime.h>

#define B_SZ 2
#define C_IN 384
#define N_TOK 2048
#define HEADS 8
#define DH 48
#define J3 1152
// ATTN_SCALE * log2(e): S is computed in log2 domain (v_exp_f32 is 2^x)
#define QSCALE_LOG2 0.20823509110768f
#define KSPLIT 4
#define KEYS_PER_SPLIT 512               // N_TOK / KSPLIT
#define DEFER_THR 11.0f                  // P bounded by 2^11 = 2048 (fp16-safe)

typedef __attribute__((ext_vector_type(8))) _Float16 f16x8;
typedef __attribute__((ext_vector_type(4))) _Float16 f16x4;
typedef __attribute__((ext_vector_type(4))) float f32x4;

__device__ __forceinline__ unsigned short f2h(float f) {
  _Float16 h = (_Float16)f;           // RNE convert
  return __builtin_bit_cast(unsigned short, h);
}
__device__ __forceinline__ uint pk2(float a, float b) {
  return __builtin_bit_cast(uint, __builtin_amdgcn_cvt_pkrtz(a, b));
}
__device__ __forceinline__ float exp2g(float x) {
  return __builtin_amdgcn_exp2f(x);
}

// ---------------- kernel 1: QKV GEMM + w_out transpose side-job ------------
// grid (32, 19): by<18 = QKV GEMM blocks; by==18 = 32 blocks transposing
// w_out -> woh[c][k] fp16 (off the critical path).
__global__ __launch_bounds__(256) void qkv_mfma(
    const float* __restrict__ x, const float* __restrict__ wq,
    const float* __restrict__ wo, unsigned short* __restrict__ Qo,
    unsigned short* __restrict__ Ko, unsigned short* __restrict__ Vo,
    unsigned short* __restrict__ woh) {
  __shared__ __align__(16) unsigned short Ts[128][72];
  __shared__ __align__(16) unsigned short Ws[64][72];
  __shared__ __align__(16) unsigned short Xt[64][132];  // bounce: [c][m], pad 132
  __shared__ __align__(16) unsigned short Wt[64][68];   // bounce: [c][j] / tr tile
  const int tid = threadIdx.x;

  if (blockIdx.y == 18) {
    // ---- w_out transpose: wo[k][c] -> woh[c][k], 36 tiles, 32 blocks ----
    for (int tile = blockIdx.x; tile < 36; tile += 32) {
      const int r0 = (tile / 6) * 64;    // k rows
      const int c0 = (tile % 6) * 64;    // c cols
      const int cc = tid & 63;
#pragma unroll
      for (int i = 0; i < 16; ++i) {
        const int rr = 4 * i + (tid >> 6);
        Wt[cc][rr] = f2h(wo[(size_t)(r0 + rr) * C_IN + c0 + cc]);
      }
      __syncthreads();
      const int cc2 = tid >> 2;
      const int seg = (tid & 3) * 16;
      uint v[8];
#pragma unroll
      for (int k = 0; k < 8; ++k)
        v[k] = (uint)Wt[cc2][seg + 2 * k] | ((uint)Wt[cc2][seg + 2 * k + 1] << 16);
      unsigned short* dp = woh + (size_t)(c0 + cc2) * C_IN + r0 + seg;
      *(uint4*)dp = make_uint4(v[0], v[1], v[2], v[3]);
      *(uint4*)(dp + 8) = make_uint4(v[4], v[5], v[6], v[7]);
      __syncthreads();
    }
    return;
  }

  const int w = tid >> 6, lane = tid & 63;
  const int lc = lane & 15, lg = lane >> 4;
  const int m0 = blockIdx.x * 128;
  const int j0 = blockIdx.y * 64;
  const int b = m0 >> 11;
  const int n0 = m0 & 2047;

  f32x4 acc[2][4];
#pragma unroll
  for (int i = 0; i < 2; ++i)
#pragma unroll
    for (int j = 0; j < 4; ++j) acc[i][j] = (f32x4){0.f, 0.f, 0.f, 0.f};

  const float* xbase = x + (size_t)b * C_IN * N_TOK + n0;

  for (int kk = 0; kk < C_IN; kk += 64) {
    // ---- stage 1: coalesced fp32 loads -> fp16 -> natural-layout bounce ----
#pragma unroll
    for (int i = 0; i < 8; ++i) {                 // x tile: 64 c x 128 n
      const int f = tid + 256 * i;
      const int c = f >> 5, m4 = (f & 31) * 4;
      const float4 v = *(const float4*)(xbase + (size_t)(kk + c) * N_TOK + m4);
      ushort4 h;
      h.x = f2h(v.x); h.y = f2h(v.y); h.z = f2h(v.z); h.w = f2h(v.w);
      *(ushort4*)&Xt[c][m4] = h;
    }
#pragma unroll
    for (int i = 0; i < 4; ++i) {                 // w tile: 64 c x 64 j
      const int f = tid + 256 * i;
      const int c = f >> 4, j4 = (f & 15) * 4;
      const float4 v = *(const float4*)(wq + (size_t)(kk + c) * J3 + j0 + j4);
      ushort4 h;
      h.x = f2h(v.x); h.y = f2h(v.y); h.z = f2h(v.z); h.w = f2h(v.w);
      *(ushort4*)&Wt[c][j4] = h;
    }
    __syncthreads();

    // ---- stage 2: transpose bounce -> MFMA tiles (paired u32 reads:
    //      columns 2p,2p+1 are adjacent -> one u32 read feeds two rows) ----
    {
      const int p = tid >> 2, q = tid & 3;         // Ts: column-pair p, c-quarter q
      unsigned short ta[16], tb[16];
#pragma unroll
      for (int s = 0; s < 16; ++s) {
        const uint v = *(const uint*)&Xt[q * 16 + s][2 * p];
        ta[s] = (unsigned short)(v & 0xffff);
        tb[s] = (unsigned short)(v >> 16);
      }
#pragma unroll
      for (int j2 = 0; j2 < 4; ++j2) {
        *(ushort4*)&Ts[2 * p][q * 16 + 4 * j2] =
            make_ushort4(ta[4 * j2], ta[4 * j2 + 1], ta[4 * j2 + 2], ta[4 * j2 + 3]);
        *(ushort4*)&Ts[2 * p + 1][q * 16 + 4 * j2] =
            make_ushort4(tb[4 * j2], tb[4 * j2 + 1], tb[4 * j2 + 2], tb[4 * j2 + 3]);
      }
      const int p2 = tid >> 3, q2 = tid & 7;       // Ws: row-pair p2, c-octant q2
      unsigned short wa[8], wb[8];
#pragma unroll
      for (int s = 0; s < 8; ++s) {
        const uint v = *(const uint*)&Wt[q2 * 8 + s][2 * p2];
        wa[s] = (unsigned short)(v & 0xffff);
        wb[s] = (unsigned short)(v >> 16);
      }
#pragma unroll
      for (int j2 = 0; j2 < 2; ++j2) {
        *(ushort4*)&Ws[2 * p2][q2 * 8 + 4 * j2] =
            make_ushort4(wa[4 * j2], wa[4 * j2 + 1], wa[4 * j2 + 2], wa[4 * j2 + 3]);
        *(ushort4*)&Ws[2 * p2 + 1][q2 * 8 + 4 * j2] =
            make_ushort4(wb[4 * j2], wb[4 * j2 + 1], wb[4 * j2 + 2], wb[4 * j2 + 3]);
      }
    }
    __syncthreads();

    // ---- MFMA (unchanged) ----
    f16x8 a[2][2], bf[4][2];
#pragma unroll
    for (int mt = 0; mt < 2; ++mt)
#pragma unroll
      for (int kh = 0; kh < 2; ++kh)
        a[mt][kh] = *(const f16x8*)&Ts[32 * w + 16 * mt + lc][32 * kh + 8 * lg];
#pragma unroll
    for (int jt = 0; jt < 4; ++jt)
#pragma unroll
      for (int kh = 0; kh < 2; ++kh)
        bf[jt][kh] = *(const f16x8*)&Ws[16 * jt + lc][32 * kh + 8 * lg];
#pragma unroll
    for (int mt = 0; mt < 2; ++mt)
#pragma unroll
      for (int jt = 0; jt < 4; ++jt)
#pragma unroll
        for (int kh = 0; kh < 2; ++kh)
          acc[mt][jt] = __builtin_amdgcn_mfma_f32_16x16x32_f16(a[mt][kh], bf[jt][kh], acc[mt][jt], 0, 0, 0);
    __syncthreads();
  }

  if (j0 >= 768) {
    // -------- V path: LDS transpose then coalesced row stores --------
    unsigned short* Tv = &Ts[0][0];   // viewed as [64 j][136 m]
#pragma unroll
    for (int jt = 0; jt < 4; ++jt)
#pragma unroll
      for (int mt = 0; mt < 2; ++mt)
#pragma unroll
        for (int r = 0; r < 4; ++r)
          Tv[(16 * jt + lc) * 136 + (32 * w + 16 * mt + 4 * lg + r)] =
              f2h(acc[mt][jt][r]);
    __syncthreads();
#pragma unroll
    for (int i = 0; i < 4; ++i) {
      const int s = tid + i * 256;
      const int row = s >> 4;
      const int segoff = (s & 15) * 8;
      const int rr2 = j0 - 768 + row;
      const int head = rr2 / DH;
      const int d = rr2 - head * DH;
      const int bh = b * HEADS + head;
      *(uint4*)(Vo + ((size_t)bh * DH + d) * N_TOK + n0 + segoff) =
          *(const uint4*)&Tv[row * 136 + segoff];
    }
  } else {
    // -------- Q/K path: direct stores --------
#pragma unroll
    for (int jt = 0; jt < 4; ++jt) {
      const int jlo = j0 + 16 * jt;
      const int which = jlo / 384;
      const int rr = jlo - which * 384;
      const int head = rr / DH;
      const int dbase = rr - head * DH;
      const int d = dbase + lc;
      const int bh = b * HEADS + head;
#pragma unroll
      for (int mt = 0; mt < 2; ++mt)
#pragma unroll
        for (int r = 0; r < 4; ++r) {
          const int n = (m0 + 32 * w + 16 * mt + 4 * lg + r) & 2047;
          float val = fminf(fmaxf(acc[mt][jt][r], -5.f), 5.f);
          if (which == 0) {
            Qo[((size_t)bh * N_TOK + n) * DH + d] = f2h(val * QSCALE_LOG2);
          } else {
            Ko[((size_t)bh * N_TOK + n) * DH + d] = f2h(val);
          }
        }
    }
  }
}

// ---------------- kernel 2: flash attention, fp16 MFMA, 4-way K-split ------
__global__ __launch_bounds__(512) void attn_kernel(
    const unsigned short* __restrict__ Q, const unsigned short* __restrict__ K,
    const unsigned short* __restrict__ Vt, unsigned short* __restrict__ Opart,
    float2* __restrict__ ml) {
  const int qt = blockIdx.x, bh = blockIdx.y, ks = blockIdx.z;
  const int b = bh >> 3, h = bh & 7;
  const int n0 = qt * 128;
  const int tid = threadIdx.x;
  const int w = tid >> 6, lane = tid & 63;
  const int lc = lane & 15, lg = lane >> 4;

  __shared__ __align__(16) unsigned short Ks[2][64][56];  // [buf][key][d +pad]
  __shared__ __align__(16) unsigned short Vs[2][48][68];  // [buf][d][key +pad]

  const unsigned short* Qrow = Q + ((size_t)bh * N_TOK + n0 + 16 * w + lc) * DH;
  const f16x8 qf0 = *(const f16x8*)(Qrow + 8 * lg);
  f16x8 qf1 = {0, 0, 0, 0, 0, 0, 0, 0};
  {
    const f16x4 t = *(const f16x4*)(Qrow + 32 + 4 * lg);
    qf1[0] = t[0]; qf1[1] = t[1]; qf1[2] = t[2]; qf1[3] = t[3];
  }

  const unsigned short* Kg = K + (size_t)bh * N_TOK * DH + (size_t)ks * KEYS_PER_SPLIT * DH;
  const uint* Vg32 = (const uint*)(Vt + (size_t)bh * DH * N_TOK) + ks * (KEYS_PER_SPLIT / 2);

  uint kr[3], vr[3];
  auto issue = [&](int t0) {
    const uint* Ksrc = (const uint*)(Kg + (size_t)t0 * DH);
#pragma unroll
    for (int i = 0; i < 3; ++i) {
      const int dw = tid + i * 512;
      kr[i] = Ksrc[dw];
      vr[i] = Vg32[(size_t)(dw >> 5) * 1024 + (t0 >> 1) + (dw & 31)];
    }
  };
  auto commit = [&](int buf) {
#pragma unroll
    for (int i = 0; i < 3; ++i) {
      const int dw = tid + i * 512;
      const int key = dw / 24, c = dw - key * 24;
      *(uint*)&Ks[buf][key][2 * c] = kr[i];
      *(uint*)&Vs[buf][dw >> 5][2 * (dw & 31)] = vr[i];
    }
  };

  float m_run = -1e30f, l_run = 0.f;
  f32x4 oacc[3] = {{0,0,0,0},{0,0,0,0},{0,0,0,0}};

  issue(0);
  commit(0);

  for (int t = 0; t < KEYS_PER_SPLIT / 64; ++t) {
    const int cur = t & 1;
    if (t < KEYS_PER_SPLIT / 64 - 1) issue((t + 1) * 64);  // overlap with compute
    __syncthreads();   // commit(cur) from prev iter visible; prev reads done

    f32x4 sac[4];
    __builtin_amdgcn_s_setprio(1);
#pragma unroll
    for (int it = 0; it < 4; ++it) {
      const int krow = 16 * it + lc;
      const f16x8 kf0 = *(const f16x8*)&Ks[cur][krow][8 * lg];
      f16x8 kf1 = {0, 0, 0, 0, 0, 0, 0, 0};
      const f16x4 tt = *(const f16x4*)&Ks[cur][krow][32 + 4 * lg];
      kf1[0] = tt[0]; kf1[1] = tt[1]; kf1[2] = tt[2]; kf1[3] = tt[3];
      const f32x4 z = {0.f, 0.f, 0.f, 0.f};
      f32x4 s = __builtin_amdgcn_mfma_f32_16x16x32_f16(kf0, qf0, z, 0, 0, 0);
      sac[it]  = __builtin_amdgcn_mfma_f32_16x16x32_f16(kf1, qf1, s, 0, 0, 0);
    }
    __builtin_amdgcn_s_setprio(0);

    float mt = -1e30f;
#pragma unroll
    for (int it = 0; it < 4; ++it)
#pragma unroll
      for (int r = 0; r < 4; ++r) mt = fmaxf(mt, sac[it][r]);
    mt = fmaxf(mt, __shfl_xor(mt, 16, 64));
    mt = fmaxf(mt, __shfl_xor(mt, 32, 64));

    // defer-max: skip rescale while row max grows by <= THR (P <= 2^THR)
    if (!__all(mt - m_run <= DEFER_THR)) {
      const float mn = fmaxf(m_run, mt);
      const float rs = exp2g(m_run - mn);   // 0 on first tile
      m_run = mn;
      l_run *= rs;
#pragma unroll
      for (int itd = 0; itd < 3; ++itd)
#pragma unroll
        for (int r = 0; r < 4; ++r) oacc[itd][r] *= rs;
    }

    float p[4][4];
    float ps = 0.f;
#pragma unroll
    for (int it = 0; it < 4; ++it)
#pragma unroll
      for (int r = 0; r < 4; ++r) {
        p[it][r] = exp2g(sac[it][r] - m_run);
        ps += p[it][r];
      }
    ps += __shfl_xor(ps, 16, 64);
    ps += __shfl_xor(ps, 32, 64);
    l_run += ps;

    f16x8 pt[2];
#pragma unroll
    for (int ks2 = 0; ks2 < 2; ++ks2) {
      union { f16x8 v; uint u[4]; } pu;
      pu.u[0] = pk2(p[2 * ks2][0], p[2 * ks2][1]);
      pu.u[1] = pk2(p[2 * ks2][2], p[2 * ks2][3]);
      pu.u[2] = pk2(p[2 * ks2 + 1][0], p[2 * ks2 + 1][1]);
      pu.u[3] = pk2(p[2 * ks2 + 1][2], p[2 * ks2 + 1][3]);
      pt[ks2] = pu.v;
    }

    __builtin_amdgcn_s_setprio(1);
#pragma unroll
    for (int itd = 0; itd < 3; ++itd) {
      const int drow = 16 * itd + lc;
#pragma unroll
      for (int ks2 = 0; ks2 < 2; ++ks2) {
        const f16x4 v0 = *(const f16x4*)&Vs[cur][drow][4 * lg + 32 * ks2];
        const f16x4 v1 = *(const f16x4*)&Vs[cur][drow][4 * lg + 32 * ks2 + 16];
        f16x8 vf;
        vf[0] = v0[0]; vf[1] = v0[1]; vf[2] = v0[2]; vf[3] = v0[3];
        vf[4] = v1[0]; vf[5] = v1[1]; vf[6] = v1[2]; vf[7] = v1[3];
        oacc[itd] = __builtin_amdgcn_mfma_f32_16x16x32_f16(vf, pt[ks2], oacc[itd], 0, 0, 0);
      }
    }
    __builtin_amdgcn_s_setprio(0);

    if (t < KEYS_PER_SPLIT / 64 - 1) commit(cur ^ 1);  // vmcnt wait auto-inserted
  }

  // epilogue: l-NORMALIZED partial (bounded by |V|max, fp16-safe) + (m,l)
  if (lg == 0)
    ml[(size_t)(ks * 16 + bh) * N_TOK + n0 + 16 * w + lc] = make_float2(m_run, l_run);
  const float inv = 1.f / l_run;
  unsigned short* Ap = Opart +
      ((size_t)(ks * B_SZ + b) * N_TOK + n0 + 16 * w + lc) * 384 + h * DH;
#pragma unroll
  for (int itd = 0; itd < 3; ++itd) {
    uint2 pkv;
    pkv.x = pk2(oacc[itd][0] * inv, oacc[itd][1] * inv);
    pkv.y = pk2(oacc[itd][2] * inv, oacc[itd][3] * inv);
    *(uint2*)(Ap + 16 * itd + 4 * lg) = pkv;
  }
}

// ---------------- kernel 3: out projection + ONE-TIME fused combine --------
// grid (2 c-halves, 256 m-tiles), 256 thr. BM=16 (was 32): LDS 40.7 KB ->
// 3 blocks/CU (was 1) -- proj was latency-bound at 1 block/CU.
__global__ __launch_bounds__(256) void proj_mfma(
    const unsigned short* __restrict__ Opart, const float2* __restrict__ ml,
    const unsigned short* __restrict__ woh, const float* __restrict__ b_out,
    const float* __restrict__ x, float* __restrict__ out) {
  __shared__ __align__(16) unsigned short Bp[16][392];  // combined AO [m][k]
  __shared__ __align__(16) unsigned short As[192][72];  // w_out [c_out][k-chunk]
  __shared__ float4 SW[16][8];                          // combine weights
  const int tid = threadIdx.x;
  const int w = tid >> 6, lane = tid & 63;
  const int lc = lane & 15, lg = lane >> 4;
  const int c0 = blockIdx.x * 192;
  const int m0 = blockIdx.y * 16;
  const int b = m0 >> 11;
  const int n0 = m0 & 2047;
  const size_t PS = (size_t)B_SZ * N_TOK * 384;

  // ---- phase A: combine weights for this block's 16 rows x 8 heads ----
  if (tid < 128) {
    const int mm = tid >> 3, hh = tid & 7;
    const int n = n0 + mm;
    const int bh = b * 8 + hh;
    const float2 e0 = ml[(size_t)(0 * 16 + bh) * N_TOK + n];
    const float2 e1 = ml[(size_t)(1 * 16 + bh) * N_TOK + n];
    const float2 e2 = ml[(size_t)(2 * 16 + bh) * N_TOK + n];
    const float2 e3 = ml[(size_t)(3 * 16 + bh) * N_TOK + n];
    const float M = fmaxf(fmaxf(e0.x, e1.x), fmaxf(e2.x, e3.x));
    const float g0 = exp2g(e0.x - M) * e0.y, g1 = exp2g(e1.x - M) * e1.y;
    const float g2 = exp2g(e2.x - M) * e2.y, g3 = exp2g(e3.x - M) * e3.y;
    const float ginv = 1.f / (g0 + g1 + g2 + g3);
    SW[mm][hh] = make_float4(g0 * ginv, g1 * ginv, g2 * ginv, g3 * ginv);
  }
  __syncthreads();

  // ---- phase B: blend 4 partials -> Bp, ONCE (768 vec8 segments) ----
#pragma unroll
  for (int i = 0; i < 3; ++i) {
    const int idx = tid + 256 * i;
    const int mm = idx / 48, seg = idx - mm * 48;   // 48 vec8 segs per row
    const int ce = seg * 8;
    const float4 s4 = SW[mm][ce / 48];              // 48 % 8 == 0: head uniform
    const size_t o = ((size_t)b * N_TOK + n0 + mm) * 384 + ce;
    union U8 { uint4 q; _Float16 e[8]; } u0, u1, u2, u3, r;
    u0.q = *(const uint4*)(Opart + 0 * PS + o);
    u1.q = *(const uint4*)(Opart + 1 * PS + o);
    u2.q = *(const uint4*)(Opart + 2 * PS + o);
    u3.q = *(const uint4*)(Opart + 3 * PS + o);
#pragma unroll
    for (int k = 0; k < 8; k += 2) {
      const float a = (float)u0.e[k] * s4.x + (float)u1.e[k] * s4.y +
                      (float)u2.e[k] * s4.z + (float)u3.e[k] * s4.w;
      const float bb = (float)u0.e[k + 1] * s4.x + (float)u1.e[k + 1] * s4.y +
                       (float)u2.e[k + 1] * s4.z + (float)u3.e[k + 1] * s4.w;
      *(uint*)&r.e[k] = pk2(a, bb);
    }
    *(uint4*)&Bp[mm][ce] = r.q;
  }
  __syncthreads();

  f32x4 acc[3];
#pragma unroll
  for (int i = 0; i < 3; ++i) acc[i] = (f32x4){0.f, 0.f, 0.f, 0.f};

  for (int kk = 0; kk < C_IN; kk += 64) {
    // ---- As staging: direct vectorized copy from woh (k-contiguous) ----
#pragma unroll
    for (int i = 0; i < 6; ++i) {
      const int f = tid + 256 * i;
      const int row = f >> 3, u4 = f & 7;           // 8 uint4 per row
      *(uint4*)&As[row][u4 * 8] =
          *(const uint4*)(woh + (size_t)(c0 + row) * C_IN + kk + u4 * 8);
    }
    __syncthreads();

    // ---- MFMA: wave w owns c-frags [48w, 48w+48) ----
    f16x8 a[3], bf[2];
#pragma unroll
    for (int ct = 0; ct < 3; ++ct)
      a[ct] = *(const f16x8*)&As[48 * w + 16 * ct + lc][8 * lg];
#pragma unroll
    for (int kh = 0; kh < 2; ++kh)
      bf[kh] = *(const f16x8*)&Bp[lc][kk + 32 * kh + 8 * lg];
    f16x8 a2[3];
#pragma unroll
    for (int ct = 0; ct < 3; ++ct)
      a2[ct] = *(const f16x8*)&As[48 * w + 16 * ct + lc][32 + 8 * lg];
#pragma unroll
    for (int ct = 0; ct < 3; ++ct) {
      acc[ct] = __builtin_amdgcn_mfma_f32_16x16x32_f16(a[ct], bf[0], acc[ct], 0, 0, 0);
      acc[ct] = __builtin_amdgcn_mfma_f32_16x16x32_f16(a2[ct], bf[1], acc[ct], 0, 0, 0);
    }
    __syncthreads();
  }

  // ---- epilogue: out = x + bias + acc ----
#pragma unroll
  for (int ct = 0; ct < 3; ++ct)
#pragma unroll
    for (int r = 0; r < 4; ++r) {
      const int c = c0 + 48 * w + 16 * ct + 4 * lg + r;
      const float bias = b_out[c];
      const int n = n0 + lc;
      const size_t off = ((size_t)b * C_IN + c) * N_TOK + n;
      out[off] = x[off] + bias + acc[ct][r];
    }
}

// ---------------- launch ----------------
extern "C" void kernel_launch(void* const* d_in, const int* in_sizes, int n_in,
                              void* d_out, int out_size, void* d_ws, size_t ws_size,
                              hipStream_t stream) {
  const float* x     = (const float*)d_in[0];
  const float* w_qkv = (const float*)d_in[1];
  const float* w_out = (const float*)d_in[2];
  const float* b_out = (const float*)d_in[3];
  float* out = (float*)d_out;

  char* ws = (char*)d_ws;
  unsigned short* Qb    = (unsigned short*)(ws);             //  3,145,728 B
  unsigned short* Kb    = (unsigned short*)(ws + 3145728);   //  3,145,728 B
  unsigned short* Vb    = (unsigned short*)(ws + 6291456);   //  3,145,728 B
  unsigned short* Opart = (unsigned short*)(ws + 9437184);   // 12,582,912 B (4 parts)
  float2*         mlb   = (float2*)(ws + 22020096);          //  1,048,576 B
  unsigned short* woh   = (unsigned short*)(ws + 23068672);  //    294,912 B

  qkv_mfma<<<dim3(32, 19), 256, 0, stream>>>(x, w_qkv, w_out, Qb, Kb, Vb, woh);
  attn_kernel<<<dim3(16, 16, KSPLIT), 512, 0, stream>>>(Qb, Kb, Vb, Opart, mlb);
  proj_mfma<<<dim3(2, 256), 256, 0, stream>>>(Opart, mlb, woh, b_out, x, out);
}

// Round 18
// 66.158 us; speedup vs baseline: 1.1323x; 1.1323x over previous
//
#include <hip/hip_runtime.h>

#define B_SZ 2
#define C_IN 384
#define N_TOK 2048
#define HEADS 8
#define DH 48
#define J3 1152
// ATTN_SCALE * log2(e): S is computed in log2 domain (v_exp_f32 is 2^x)
#define QSCALE_LOG2 0.20823509110768f
#define KSPLIT 4
#define KEYS_PER_SPLIT 512               // N_TOK / KSPLIT
#define DEFER_THR 11.0f                  // P bounded by 2^11 = 2048 (fp16-safe)

typedef __attribute__((ext_vector_type(8))) _Float16 f16x8;
typedef __attribute__((ext_vector_type(4))) _Float16 f16x4;
typedef __attribute__((ext_vector_type(4))) float f32x4;

__device__ __forceinline__ unsigned short f2h(float f) {
  _Float16 h = (_Float16)f;           // RNE convert
  return __builtin_bit_cast(unsigned short, h);
}
__device__ __forceinline__ uint pk2(float a, float b) {
  return __builtin_bit_cast(uint, __builtin_amdgcn_cvt_pkrtz(a, b));
}
__device__ __forceinline__ float exp2g(float x) {
  return __builtin_amdgcn_exp2f(x);
}

// ---------------- kernel 1: QKV GEMM + w_out transpose side-job ------------
// grid (32, 19): by<18 = QKV GEMM blocks; by==18 = 32 blocks transposing
// w_out -> woh[c][k] fp16 (off the critical path).
__global__ __launch_bounds__(256) void qkv_mfma(
    const float* __restrict__ x, const float* __restrict__ wq,
    const float* __restrict__ wo, unsigned short* __restrict__ Qo,
    unsigned short* __restrict__ Ko, unsigned short* __restrict__ Vo,
    unsigned short* __restrict__ woh) {
  __shared__ __align__(16) unsigned short Ts[128][72];
  __shared__ __align__(16) unsigned short Ws[64][72];
  __shared__ __align__(16) unsigned short Xt[64][132];  // bounce: [c][m], pad 132
  __shared__ __align__(16) unsigned short Wt[64][68];   // bounce: [c][j] / tr tile
  const int tid = threadIdx.x;

  if (blockIdx.y == 18) {
    // ---- w_out transpose: wo[k][c] -> woh[c][k], 36 tiles, 32 blocks ----
    for (int tile = blockIdx.x; tile < 36; tile += 32) {
      const int r0 = (tile / 6) * 64;    // k rows
      const int c0 = (tile % 6) * 64;    // c cols
      const int cc = tid & 63;
#pragma unroll
      for (int i = 0; i < 16; ++i) {
        const int rr = 4 * i + (tid >> 6);
        Wt[cc][rr] = f2h(wo[(size_t)(r0 + rr) * C_IN + c0 + cc]);
      }
      __syncthreads();
      const int cc2 = tid >> 2;
      const int seg = (tid & 3) * 16;
      uint v[8];
#pragma unroll
      for (int k = 0; k < 8; ++k)
        v[k] = (uint)Wt[cc2][seg + 2 * k] | ((uint)Wt[cc2][seg + 2 * k + 1] << 16);
      unsigned short* dp = woh + (size_t)(c0 + cc2) * C_IN + r0 + seg;
      *(uint4*)dp = make_uint4(v[0], v[1], v[2], v[3]);
      *(uint4*)(dp + 8) = make_uint4(v[4], v[5], v[6], v[7]);
      __syncthreads();
    }
    return;
  }

  const int w = tid >> 6, lane = tid & 63;
  const int lc = lane & 15, lg = lane >> 4;
  const int m0 = blockIdx.x * 128;
  const int j0 = blockIdx.y * 64;
  const int b = m0 >> 11;
  const int n0 = m0 & 2047;

  f32x4 acc[2][4];
#pragma unroll
  for (int i = 0; i < 2; ++i)
#pragma unroll
    for (int j = 0; j < 4; ++j) acc[i][j] = (f32x4){0.f, 0.f, 0.f, 0.f};

  const float* xbase = x + (size_t)b * C_IN * N_TOK + n0;

  for (int kk = 0; kk < C_IN; kk += 64) {
    // ---- stage 1: coalesced fp32 loads -> fp16 -> natural-layout bounce ----
#pragma unroll
    for (int i = 0; i < 8; ++i) {                 // x tile: 64 c x 128 n
      const int f = tid + 256 * i;
      const int c = f >> 5, m4 = (f & 31) * 4;
      const float4 v = *(const float4*)(xbase + (size_t)(kk + c) * N_TOK + m4);
      ushort4 h;
      h.x = f2h(v.x); h.y = f2h(v.y); h.z = f2h(v.z); h.w = f2h(v.w);
      *(ushort4*)&Xt[c][m4] = h;
    }
#pragma unroll
    for (int i = 0; i < 4; ++i) {                 // w tile: 64 c x 64 j
      const int f = tid + 256 * i;
      const int c = f >> 4, j4 = (f & 15) * 4;
      const float4 v = *(const float4*)(wq + (size_t)(kk + c) * J3 + j0 + j4);
      ushort4 h;
      h.x = f2h(v.x); h.y = f2h(v.y); h.z = f2h(v.z); h.w = f2h(v.w);
      *(ushort4*)&Wt[c][j4] = h;
    }
    __syncthreads();

    // ---- stage 2: transpose bounce -> MFMA-ready k-contiguous tiles ----
    {
      const int m = tid >> 1, ks = (tid & 1) * 32;   // Ts rows
      unsigned short tmp[32];
#pragma unroll
      for (int j2 = 0; j2 < 32; ++j2) tmp[j2] = Xt[ks + j2][m];
#pragma unroll
      for (int j2 = 0; j2 < 8; ++j2)
        *(ushort4*)&Ts[m][ks + 4 * j2] =
            make_ushort4(tmp[4 * j2], tmp[4 * j2 + 1], tmp[4 * j2 + 2], tmp[4 * j2 + 3]);
      const int jj = tid >> 2, ks2 = (tid & 3) * 16;  // Ws rows
      unsigned short tw[16];
#pragma unroll
      for (int i2 = 0; i2 < 16; ++i2) tw[i2] = Wt[ks2 + i2][jj];
#pragma unroll
      for (int i2 = 0; i2 < 4; ++i2)
        *(ushort4*)&Ws[jj][ks2 + 4 * i2] =
            make_ushort4(tw[4 * i2], tw[4 * i2 + 1], tw[4 * i2 + 2], tw[4 * i2 + 3]);
    }
    __syncthreads();

    // ---- MFMA (unchanged) ----
    f16x8 a[2][2], bf[4][2];
#pragma unroll
    for (int mt = 0; mt < 2; ++mt)
#pragma unroll
      for (int kh = 0; kh < 2; ++kh)
        a[mt][kh] = *(const f16x8*)&Ts[32 * w + 16 * mt + lc][32 * kh + 8 * lg];
#pragma unroll
    for (int jt = 0; jt < 4; ++jt)
#pragma unroll
      for (int kh = 0; kh < 2; ++kh)
        bf[jt][kh] = *(const f16x8*)&Ws[16 * jt + lc][32 * kh + 8 * lg];
#pragma unroll
    for (int mt = 0; mt < 2; ++mt)
#pragma unroll
      for (int jt = 0; jt < 4; ++jt)
#pragma unroll
        for (int kh = 0; kh < 2; ++kh)
          acc[mt][jt] = __builtin_amdgcn_mfma_f32_16x16x32_f16(a[mt][kh], bf[jt][kh], acc[mt][jt], 0, 0, 0);
    __syncthreads();
  }

  if (j0 >= 768) {
    // -------- V path: LDS transpose then coalesced row stores --------
    unsigned short* Tv = &Ts[0][0];   // viewed as [64 j][136 m]
#pragma unroll
    for (int jt = 0; jt < 4; ++jt)
#pragma unroll
      for (int mt = 0; mt < 2; ++mt)
#pragma unroll
        for (int r = 0; r < 4; ++r)
          Tv[(16 * jt + lc) * 136 + (32 * w + 16 * mt + 4 * lg + r)] =
              f2h(acc[mt][jt][r]);
    __syncthreads();
#pragma unroll
    for (int i = 0; i < 4; ++i) {
      const int s = tid + i * 256;
      const int row = s >> 4;
      const int segoff = (s & 15) * 8;
      const int rr2 = j0 - 768 + row;
      const int head = rr2 / DH;
      const int d = rr2 - head * DH;
      const int bh = b * HEADS + head;
      *(uint4*)(Vo + ((size_t)bh * DH + d) * N_TOK + n0 + segoff) =
          *(const uint4*)&Tv[row * 136 + segoff];
    }
  } else {
    // -------- Q/K path: direct stores --------
#pragma unroll
    for (int jt = 0; jt < 4; ++jt) {
      const int jlo = j0 + 16 * jt;
      const int which = jlo / 384;
      const int rr = jlo - which * 384;
      const int head = rr / DH;
      const int dbase = rr - head * DH;
      const int d = dbase + lc;
      const int bh = b * HEADS + head;
#pragma unroll
      for (int mt = 0; mt < 2; ++mt)
#pragma unroll
        for (int r = 0; r < 4; ++r) {
          const int n = (m0 + 32 * w + 16 * mt + 4 * lg + r) & 2047;
          float val = fminf(fmaxf(acc[mt][jt][r], -5.f), 5.f);
          if (which == 0) {
            Qo[((size_t)bh * N_TOK + n) * DH + d] = f2h(val * QSCALE_LOG2);
          } else {
            Ko[((size_t)bh * N_TOK + n) * DH + d] = f2h(val);
          }
        }
    }
  }
}

// ---------------- kernel 2: flash attention, fp16 MFMA, 4-way K-split ------
__global__ __launch_bounds__(512) void attn_kernel(
    const unsigned short* __restrict__ Q, const unsigned short* __restrict__ K,
    const unsigned short* __restrict__ Vt, unsigned short* __restrict__ Opart,
    float2* __restrict__ ml) {
  const int qt = blockIdx.x, bh = blockIdx.y, ks = blockIdx.z;
  const int b = bh >> 3, h = bh & 7;
  const int n0 = qt * 128;
  const int tid = threadIdx.x;
  const int w = tid >> 6, lane = tid & 63;
  const int lc = lane & 15, lg = lane >> 4;

  __shared__ __align__(16) unsigned short Ks[2][64][56];  // [buf][key][d +pad]
  __shared__ __align__(16) unsigned short Vs[2][48][68];  // [buf][d][key +pad]

  const unsigned short* Qrow = Q + ((size_t)bh * N_TOK + n0 + 16 * w + lc) * DH;
  const f16x8 qf0 = *(const f16x8*)(Qrow + 8 * lg);
  f16x8 qf1 = {0, 0, 0, 0, 0, 0, 0, 0};
  {
    const f16x4 t = *(const f16x4*)(Qrow + 32 + 4 * lg);
    qf1[0] = t[0]; qf1[1] = t[1]; qf1[2] = t[2]; qf1[3] = t[3];
  }

  const unsigned short* Kg = K + (size_t)bh * N_TOK * DH + (size_t)ks * KEYS_PER_SPLIT * DH;
  const uint* Vg32 = (const uint*)(Vt + (size_t)bh * DH * N_TOK) + ks * (KEYS_PER_SPLIT / 2);

  uint kr[3], vr[3];
  auto issue = [&](int t0) {
    const uint* Ksrc = (const uint*)(Kg + (size_t)t0 * DH);
#pragma unroll
    for (int i = 0; i < 3; ++i) {
      const int dw = tid + i * 512;
      kr[i] = Ksrc[dw];
      vr[i] = Vg32[(size_t)(dw >> 5) * 1024 + (t0 >> 1) + (dw & 31)];
    }
  };
  auto commit = [&](int buf) {
#pragma unroll
    for (int i = 0; i < 3; ++i) {
      const int dw = tid + i * 512;
      const int key = dw / 24, c = dw - key * 24;
      *(uint*)&Ks[buf][key][2 * c] = kr[i];
      *(uint*)&Vs[buf][dw >> 5][2 * (dw & 31)] = vr[i];
    }
  };

  float m_run = -1e30f, l_run = 0.f;
  f32x4 oacc[3] = {{0,0,0,0},{0,0,0,0},{0,0,0,0}};

  issue(0);
  commit(0);

  for (int t = 0; t < KEYS_PER_SPLIT / 64; ++t) {
    const int cur = t & 1;
    if (t < KEYS_PER_SPLIT / 64 - 1) issue((t + 1) * 64);  // overlap with compute
    __syncthreads();   // commit(cur) from prev iter visible; prev reads done

    f32x4 sac[4];
    __builtin_amdgcn_s_setprio(1);
#pragma unroll
    for (int it = 0; it < 4; ++it) {
      const int krow = 16 * it + lc;
      const f16x8 kf0 = *(const f16x8*)&Ks[cur][krow][8 * lg];
      f16x8 kf1 = {0, 0, 0, 0, 0, 0, 0, 0};
      const f16x4 tt = *(const f16x4*)&Ks[cur][krow][32 + 4 * lg];
      kf1[0] = tt[0]; kf1[1] = tt[1]; kf1[2] = tt[2]; kf1[3] = tt[3];
      const f32x4 z = {0.f, 0.f, 0.f, 0.f};
      f32x4 s = __builtin_amdgcn_mfma_f32_16x16x32_f16(kf0, qf0, z, 0, 0, 0);
      sac[it]  = __builtin_amdgcn_mfma_f32_16x16x32_f16(kf1, qf1, s, 0, 0, 0);
    }
    __builtin_amdgcn_s_setprio(0);

    float mt = -1e30f;
#pragma unroll
    for (int it = 0; it < 4; ++it)
#pragma unroll
      for (int r = 0; r < 4; ++r) mt = fmaxf(mt, sac[it][r]);
    mt = fmaxf(mt, __shfl_xor(mt, 16, 64));
    mt = fmaxf(mt, __shfl_xor(mt, 32, 64));

    // defer-max: skip rescale while row max grows by <= THR (P <= 2^THR)
    if (!__all(mt - m_run <= DEFER_THR)) {
      const float mn = fmaxf(m_run, mt);
      const float rs = exp2g(m_run - mn);   // 0 on first tile
      m_run = mn;
      l_run *= rs;
#pragma unroll
      for (int itd = 0; itd < 3; ++itd)
#pragma unroll
        for (int r = 0; r < 4; ++r) oacc[itd][r] *= rs;
    }

    float p[4][4];
    float ps = 0.f;
#pragma unroll
    for (int it = 0; it < 4; ++it)
#pragma unroll
      for (int r = 0; r < 4; ++r) {
        p[it][r] = exp2g(sac[it][r] - m_run);
        ps += p[it][r];
      }
    ps += __shfl_xor(ps, 16, 64);
    ps += __shfl_xor(ps, 32, 64);
    l_run += ps;

    f16x8 pt[2];
#pragma unroll
    for (int ks2 = 0; ks2 < 2; ++ks2) {
      union { f16x8 v; uint u[4]; } pu;
      pu.u[0] = pk2(p[2 * ks2][0], p[2 * ks2][1]);
      pu.u[1] = pk2(p[2 * ks2][2], p[2 * ks2][3]);
      pu.u[2] = pk2(p[2 * ks2 + 1][0], p[2 * ks2 + 1][1]);
      pu.u[3] = pk2(p[2 * ks2 + 1][2], p[2 * ks2 + 1][3]);
      pt[ks2] = pu.v;
    }

    __builtin_amdgcn_s_setprio(1);
#pragma unroll
    for (int itd = 0; itd < 3; ++itd) {
      const int drow = 16 * itd + lc;
#pragma unroll
      for (int ks2 = 0; ks2 < 2; ++ks2) {
        const f16x4 v0 = *(const f16x4*)&Vs[cur][drow][4 * lg + 32 * ks2];
        const f16x4 v1 = *(const f16x4*)&Vs[cur][drow][4 * lg + 32 * ks2 + 16];
        f16x8 vf;
        vf[0] = v0[0]; vf[1] = v0[1]; vf[2] = v0[2]; vf[3] = v0[3];
        vf[4] = v1[0]; vf[5] = v1[1]; vf[6] = v1[2]; vf[7] = v1[3];
        oacc[itd] = __builtin_amdgcn_mfma_f32_16x16x32_f16(vf, pt[ks2], oacc[itd], 0, 0, 0);
      }
    }
    __builtin_amdgcn_s_setprio(0);

    if (t < KEYS_PER_SPLIT / 64 - 1) commit(cur ^ 1);  // vmcnt wait auto-inserted
  }

  // epilogue: l-NORMALIZED partial (bounded by |V|max, fp16-safe) + (m,l)
  if (lg == 0)
    ml[(size_t)(ks * 16 + bh) * N_TOK + n0 + 16 * w + lc] = make_float2(m_run, l_run);
  const float inv = 1.f / l_run;
  unsigned short* Ap = Opart +
      ((size_t)(ks * B_SZ + b) * N_TOK + n0 + 16 * w + lc) * 384 + h * DH;
#pragma unroll
  for (int itd = 0; itd < 3; ++itd) {
    uint2 pkv;
    pkv.x = pk2(oacc[itd][0] * inv, oacc[itd][1] * inv);
    pkv.y = pk2(oacc[itd][2] * inv, oacc[itd][3] * inv);
    *(uint2*)(Ap + 16 * itd + 4 * lg) = pkv;
  }
}

// ---------------- kernel 3: out projection + ONE-TIME fused combine --------
// grid (2 c-halves, 128 m-tiles), 256 thr. BM=32, BN=192. B-panel combined
// once into LDS; As loads precomputed woh directly.
__global__ __launch_bounds__(256) void proj_mfma(
    const unsigned short* __restrict__ Opart, const float2* __restrict__ ml,
    const unsigned short* __restrict__ woh, const float* __restrict__ b_out,
    const float* __restrict__ x, float* __restrict__ out) {
  __shared__ __align__(16) unsigned short Bp[32][392];  // combined AO [m][k]
  __shared__ __align__(16) unsigned short As[192][72];  // w_out [c_out][k-chunk]
  __shared__ float4 SW[32][8];                          // combine weights
  const int tid = threadIdx.x;
  const int w = tid >> 6, lane = tid & 63;
  const int lc = lane & 15, lg = lane >> 4;
  const int c0 = blockIdx.x * 192;
  const int m0 = blockIdx.y * 32;
  const int b = m0 >> 11;
  const int n0 = m0 & 2047;
  const size_t PS = (size_t)B_SZ * N_TOK * 384;

  // ---- phase A: combine weights for this block's 32 rows x 8 heads ----
  {
    const int mm = tid >> 3, hh = tid & 7;
    const int n = n0 + mm;
    const int bh = b * 8 + hh;
    const float2 e0 = ml[(size_t)(0 * 16 + bh) * N_TOK + n];
    const float2 e1 = ml[(size_t)(1 * 16 + bh) * N_TOK + n];
    const float2 e2 = ml[(size_t)(2 * 16 + bh) * N_TOK + n];
    const float2 e3 = ml[(size_t)(3 * 16 + bh) * N_TOK + n];
    const float M = fmaxf(fmaxf(e0.x, e1.x), fmaxf(e2.x, e3.x));
    const float g0 = exp2g(e0.x - M) * e0.y, g1 = exp2g(e1.x - M) * e1.y;
    const float g2 = exp2g(e2.x - M) * e2.y, g3 = exp2g(e3.x - M) * e3.y;
    const float ginv = 1.f / (g0 + g1 + g2 + g3);
    SW[mm][hh] = make_float4(g0 * ginv, g1 * ginv, g2 * ginv, g3 * ginv);
  }
  __syncthreads();

  // ---- phase B: blend 4 partials -> Bp, ONCE (1536 vec8 segments) ----
#pragma unroll
  for (int i = 0; i < 6; ++i) {
    const int idx = tid + 256 * i;
    const int mm = idx / 48, seg = idx - mm * 48;   // 48 vec8 segs per row
    const int ce = seg * 8;
    const float4 s4 = SW[mm][ce / 48];              // 48 % 8 == 0: head uniform
    const size_t o = ((size_t)b * N_TOK + n0 + mm) * 384 + ce;
    union U8 { uint4 q; _Float16 e[8]; } u0, u1, u2, u3, r;
    u0.q = *(const uint4*)(Opart + 0 * PS + o);
    u1.q = *(const uint4*)(Opart + 1 * PS + o);
    u2.q = *(const uint4*)(Opart + 2 * PS + o);
    u3.q = *(const uint4*)(Opart + 3 * PS + o);
#pragma unroll
    for (int k = 0; k < 8; k += 2) {
      const float a = (float)u0.e[k] * s4.x + (float)u1.e[k] * s4.y +
                      (float)u2.e[k] * s4.z + (float)u3.e[k] * s4.w;
      const float bb = (float)u0.e[k + 1] * s4.x + (float)u1.e[k + 1] * s4.y +
                       (float)u2.e[k + 1] * s4.z + (float)u3.e[k + 1] * s4.w;
      *(uint*)&r.e[k] = pk2(a, bb);
    }
    *(uint4*)&Bp[mm][ce] = r.q;
  }
  __syncthreads();

  f32x4 acc[3][2];
#pragma unroll
  for (int i = 0; i < 3; ++i)
#pragma unroll
    for (int j = 0; j < 2; ++j) acc[i][j] = (f32x4){0.f, 0.f, 0.f, 0.f};

  for (int kk = 0; kk < C_IN; kk += 64) {
    // ---- As staging: direct vectorized copy from woh (k-contiguous) ----
    // 192 rows x 64 k = 1536 uint4; 256 thr x 6
#pragma unroll
    for (int i = 0; i < 6; ++i) {
      const int f = tid + 256 * i;
      const int row = f >> 3, u4 = f & 7;           // 8 uint4 per row
      *(uint4*)&As[row][u4 * 8] =
          *(const uint4*)(woh + (size_t)(c0 + row) * C_IN + kk + u4 * 8);
    }
    __syncthreads();

    // ---- MFMA: wave w owns c-frags [48w, 48w+48) ----
    f16x8 a[3][2], bf[2][2];
#pragma unroll
    for (int ct = 0; ct < 3; ++ct)
#pragma unroll
      for (int kh = 0; kh < 2; ++kh)
        a[ct][kh] = *(const f16x8*)&As[48 * w + 16 * ct + lc][32 * kh + 8 * lg];
#pragma unroll
    for (int mt = 0; mt < 2; ++mt)
#pragma unroll
      for (int kh = 0; kh < 2; ++kh)
        bf[mt][kh] = *(const f16x8*)&Bp[16 * mt + lc][kk + 32 * kh + 8 * lg];
#pragma unroll
    for (int ct = 0; ct < 3; ++ct)
#pragma unroll
      for (int mt = 0; mt < 2; ++mt)
#pragma unroll
        for (int kh = 0; kh < 2; ++kh)
          acc[ct][mt] = __builtin_amdgcn_mfma_f32_16x16x32_f16(a[ct][kh], bf[mt][kh], acc[ct][mt], 0, 0, 0);
    __syncthreads();
  }

  // ---- epilogue: out = x + bias + acc ----
#pragma unroll
  for (int ct = 0; ct < 3; ++ct)
#pragma unroll
    for (int r = 0; r < 4; ++r) {
      const int c = c0 + 48 * w + 16 * ct + 4 * lg + r;
      const float bias = b_out[c];
#pragma unroll
      for (int mt = 0; mt < 2; ++mt) {
        const int n = n0 + 16 * mt + lc;
        const size_t off = ((size_t)b * C_IN + c) * N_TOK + n;
        out[off] = x[off] + bias + acc[ct][mt][r];
      }
    }
}

// ---------------- launch ----------------
extern "C" void kernel_launch(void* const* d_in, const int* in_sizes, int n_in,
                              void* d_out, int out_size, void* d_ws, size_t ws_size,
                              hipStream_t stream) {
  const float* x     = (const float*)d_in[0];
  const float* w_qkv = (const float*)d_in[1];
  const float* w_out = (const float*)d_in[2];
  const float* b_out = (const float*)d_in[3];
  float* out = (float*)d_out;

  char* ws = (char*)d_ws;
  unsigned short* Qb    = (unsigned short*)(ws);             //  3,145,728 B
  unsigned short* Kb    = (unsigned short*)(ws + 3145728);   //  3,145,728 B
  unsigned short* Vb    = (unsigned short*)(ws + 6291456);   //  3,145,728 B
  unsigned short* Opart = (unsigned short*)(ws + 9437184);   // 12,582,912 B (4 parts)
  float2*         mlb   = (float2*)(ws + 22020096);          //  1,048,576 B
  unsigned short* woh   = (unsigned short*)(ws + 23068672);  //    294,912 B

  qkv_mfma<<<dim3(32, 19), 256, 0, stream>>>(x, w_qkv, w_out, Qb, Kb, Vb, woh);
  attn_kernel<<<dim3(16, 16, KSPLIT), 512, 0, stream>>>(Qb, Kb, Vb, Opart, mlb);
  proj_mfma<<<dim3(2, 128), 256, 0, stream>>>(Opart, mlb, woh, b_out, x, out);
}